// Round 1
// baseline (2151.676 us; speedup 1.0000x reference)
//
#include <hip/hip_runtime.h>

#define NN 50000
#define EE 600000
#define DD 128
#define DD2 256
#define LL 5
#define BN_EPS 1e-5f

// ---------------- CSR build ----------------

__global__ void hist_kernel(const int* __restrict__ dst, int* __restrict__ counts) {
    int e = blockIdx.x * blockDim.x + threadIdx.x;
    if (e < EE) atomicAdd(&counts[dst[e]], 1);
}

__global__ void scan1_kernel(const int* __restrict__ counts, int* __restrict__ row_ptr,
                             int* __restrict__ blksum) {
    __shared__ int tmp[256];
    int i = blockIdx.x * 256 + threadIdx.x;
    int v = (i < NN) ? counts[i] : 0;
    tmp[threadIdx.x] = v;
    __syncthreads();
    for (int off = 1; off < 256; off <<= 1) {
        int x = 0;
        if (threadIdx.x >= off) x = tmp[threadIdx.x - off];
        __syncthreads();
        if (threadIdx.x >= off) tmp[threadIdx.x] += x;
        __syncthreads();
    }
    if (i < NN) row_ptr[i] = tmp[threadIdx.x] - v;   // exclusive
    if (threadIdx.x == 255) blksum[blockIdx.x] = tmp[255];
}

__global__ void scan2_kernel(int* __restrict__ blksum, int nblocks) {
    __shared__ int tmp[256];
    int v = (threadIdx.x < nblocks) ? blksum[threadIdx.x] : 0;
    tmp[threadIdx.x] = v;
    __syncthreads();
    for (int off = 1; off < 256; off <<= 1) {
        int x = 0;
        if (threadIdx.x >= off) x = tmp[threadIdx.x - off];
        __syncthreads();
        if (threadIdx.x >= off) tmp[threadIdx.x] += x;
        __syncthreads();
    }
    blksum[threadIdx.x] = tmp[threadIdx.x] - v;      // exclusive block offsets
}

__global__ void scan3_kernel(int* __restrict__ row_ptr, const int* __restrict__ blksum) {
    int i = blockIdx.x * 256 + threadIdx.x;
    if (i < NN) row_ptr[i] += blksum[blockIdx.x];
    if (i == 0) row_ptr[NN] = EE;
}

__global__ void scatter_kernel(const int* __restrict__ dst, const int* __restrict__ row_ptr,
                               int* __restrict__ cursor, int* __restrict__ perm) {
    int e = blockIdx.x * blockDim.x + threadIdx.x;
    if (e < EE) {
        int d = dst[e];
        int p = row_ptr[d] + atomicAdd(&cursor[d], 1);
        perm[p] = e;
    }
}

// ---------------- node init ----------------

__global__ void init_h_kernel(const int* __restrict__ x, const float* __restrict__ atom_emb,
                              float* __restrict__ h) {
    int n = blockIdx.x * 2 + (threadIdx.x >> 7);
    int d = threadIdx.x & 127;
    if (n >= NN) return;
    float acc = 0.f;
#pragma unroll
    for (int f = 0; f < 9; f++) {
        int idx = x[n * 9 + f];
        acc += atom_emb[(f * 64 + idx) * DD + d];
    }
    h[n * DD + d] = acc;
}

// ---------------- edge aggregate: z = (1+eps)*h + sum_{e: dst=n} relu(h[src]+ea)*w ----------------

__global__ void agg_kernel(const float* __restrict__ h, const int* __restrict__ row_ptr,
                           const int* __restrict__ perm, const int* __restrict__ src,
                           const int* __restrict__ edge_attr, const float* __restrict__ ew,
                           const float* __restrict__ bond_l, const float* __restrict__ eps_ptr,
                           float* __restrict__ zout) {
    int n = blockIdx.x * 2 + (threadIdx.x >> 7);
    int d = threadIdx.x & 127;
    if (n >= NN) return;
    int beg = row_ptr[n], end = row_ptr[n + 1];
    float acc = 0.f;
    for (int i = beg; i < end; i++) {
        int e = perm[i];
        int s = src[e];
        int a0 = edge_attr[3 * e + 0];
        int a1 = edge_attr[3 * e + 1];
        int a2 = edge_attr[3 * e + 2];
        float w = ew[e];
        float eav = bond_l[(0 * 8 + a0) * DD + d] + bond_l[(1 * 8 + a1) * DD + d] +
                    bond_l[(2 * 8 + a2) * DD + d];
        float m = h[(size_t)s * DD + d] + eav;
        m = fmaxf(m, 0.f) * w;
        acc += m;
    }
    float eps = eps_ptr[0];
    zout[(size_t)n * DD + d] = (1.f + eps) * h[(size_t)n * DD + d] + acc;
}

// ---------------- fp32 GEMM: C(N x M) = A(N x K) @ B(K x M) + bias; optional fused BN+relu on A ----------------

template <int K, int M, bool FUSE>
__global__ __launch_bounds__(256) void gemm_kernel(const float* __restrict__ A,
                                                   const float* __restrict__ B,
                                                   const float* __restrict__ bias,
                                                   const float* __restrict__ sN,
                                                   const float* __restrict__ tN,
                                                   float* __restrict__ C) {
    const int TILE_R = 64, TILE_C = 64, TK = 16;
    __shared__ float As[TK][TILE_R + 4];
    __shared__ float Bs[TK][TILE_C];
    int tid = threadIdx.x;
    int row0 = blockIdx.x * TILE_R;
    int col0 = blockIdx.y * TILE_C;
    int ty = tid >> 4;   // 0..15
    int tx = tid & 15;   // 0..15
    float acc[4][4] = {};
    for (int kk = 0; kk < K; kk += TK) {
#pragma unroll
        for (int i = 0; i < 4; i++) {
            int r = row0 + ty + 16 * i;
            float a = 0.f;
            if (r < NN) a = A[(size_t)r * K + kk + tx];
            if (FUSE) {
                a = fmaxf(a * sN[kk + tx] + tN[kk + tx], 0.f);
            }
            As[tx][ty + 16 * i] = a;
        }
#pragma unroll
        for (int i = 0; i < 4; i++) {
            int idx = i * 256 + tid;
            int bk = idx >> 6, bc = idx & 63;
            Bs[bk][bc] = B[(size_t)(kk + bk) * M + col0 + bc];
        }
        __syncthreads();
#pragma unroll
        for (int k = 0; k < TK; k++) {
            float av[4], bv[4];
#pragma unroll
            for (int i = 0; i < 4; i++) av[i] = As[k][ty * 4 + i];
#pragma unroll
            for (int j = 0; j < 4; j++) bv[j] = Bs[k][tx * 4 + j];
#pragma unroll
            for (int i = 0; i < 4; i++)
#pragma unroll
                for (int j = 0; j < 4; j++) acc[i][j] += av[i] * bv[j];
        }
        __syncthreads();
    }
#pragma unroll
    for (int i = 0; i < 4; i++) {
        int r = row0 + ty * 4 + i;
        if (r < NN) {
#pragma unroll
            for (int j = 0; j < 4; j++) {
                int c = col0 + tx * 4 + j;
                C[(size_t)r * M + c] = acc[i][j] + bias[c];
            }
        }
    }
}

// ---------------- per-column stats (sum, sumsq) ----------------

template <int M>
__global__ void stats_kernel(const float* __restrict__ Z, float* __restrict__ sums,
                             float* __restrict__ sumsq) {
    int c = threadIdx.x;
    int r0 = blockIdx.x * 128;
    int r1 = r0 + 128;
    if (r1 > NN) r1 = NN;
    float s = 0.f, q = 0.f;
    for (int r = r0; r < r1; r++) {
        float v = Z[(size_t)r * M + c];
        s += v;
        q += v * v;
    }
    atomicAdd(&sums[c], s);
    atomicAdd(&sumsq[c], q);
}

template <int M>
__global__ void bn_finalize_kernel(const float* __restrict__ sums, const float* __restrict__ sumsq,
                                   const float* __restrict__ g, const float* __restrict__ b,
                                   float* __restrict__ s_out, float* __restrict__ t_out) {
    int c = threadIdx.x;
    float mean = sums[c] * (1.f / NN);
    float var = sumsq[c] * (1.f / NN) - mean * mean;
    float sc = g[c] * rsqrtf(var + BN_EPS);
    s_out[c] = sc;
    t_out[c] = b[c] - mean * sc;
}

__global__ void apply_bn_kernel(const float* __restrict__ z2, const float* __restrict__ s,
                                const float* __restrict__ t, float* __restrict__ out,
                                int do_relu) {
    int i = blockIdx.x * blockDim.x + threadIdx.x;
    if (i < NN * DD) {
        int c = i & 127;
        float v = z2[i] * s[c] + t[c];
        if (do_relu) v = fmaxf(v, 0.f);
        out[i] = v;
    }
}

// ---------------- launch ----------------

extern "C" void kernel_launch(void* const* d_in, const int* in_sizes, int n_in,
                              void* d_out, int out_size, void* d_ws, size_t ws_size,
                              hipStream_t stream) {
    const int* x = (const int*)d_in[0];
    const int* edge_index = (const int*)d_in[1];
    const int* edge_attr = (const int*)d_in[2];
    const float* edge_weight = (const float*)d_in[3];
    const float* atom_emb = (const float*)d_in[4];
    const float* bond_emb = (const float*)d_in[5];
    const float* W1 = (const float*)d_in[6];
    const float* b1 = (const float*)d_in[7];
    const float* bn1_g = (const float*)d_in[8];
    const float* bn1_b = (const float*)d_in[9];
    const float* W2 = (const float*)d_in[10];
    const float* b2 = (const float*)d_in[11];
    const float* eps_p = (const float*)d_in[12];
    const float* bn_g = (const float*)d_in[13];
    const float* bn_b = (const float*)d_in[14];
    const int* src = edge_index;
    const int* dst = edge_index + EE;

    char* p = (char*)d_ws;
    auto alloc = [&](size_t bytes) {
        void* r = (void*)p;
        p += (bytes + 255) & ~(size_t)255;
        return r;
    };
    float* h = (float*)alloc((size_t)NN * DD * 4);
    float* zbuf = (float*)alloc((size_t)NN * DD * 4);
    float* z1 = (float*)alloc((size_t)NN * DD2 * 4);
    int* counts = (int*)alloc((size_t)NN * 4);
    int* row_ptr = (int*)alloc((size_t)(NN + 1) * 4);
    int* perm = (int*)alloc((size_t)EE * 4);
    int* blksum = (int*)alloc(256 * 4);
    float* stats = (float*)alloc(768 * 4);
    float* sbuf = (float*)alloc(768 * 4);
    float* z2 = zbuf;  // zbuf dead after gemm1 reads it

    // --- CSR by dst (rebuilt every call; ws is re-poisoned) ---
    hipMemsetAsync(counts, 0, (size_t)NN * 4, stream);
    hist_kernel<<<(EE + 255) / 256, 256, 0, stream>>>(dst, counts);
    int nblk = (NN + 255) / 256;  // 196
    scan1_kernel<<<nblk, 256, 0, stream>>>(counts, row_ptr, blksum);
    scan2_kernel<<<1, 256, 0, stream>>>(blksum, nblk);
    scan3_kernel<<<nblk, 256, 0, stream>>>(row_ptr, blksum);
    hipMemsetAsync(counts, 0, (size_t)NN * 4, stream);
    scatter_kernel<<<(EE + 255) / 256, 256, 0, stream>>>(dst, row_ptr, counts, perm);

    init_h_kernel<<<NN / 2, 256, 0, stream>>>(x, atom_emb, h);

    for (int l = 0; l < LL; l++) {
        agg_kernel<<<NN / 2, 256, 0, stream>>>(h, row_ptr, perm, src, edge_attr, edge_weight,
                                               bond_emb + (size_t)l * 3 * 8 * DD, eps_p + l, zbuf);

        gemm_kernel<DD, DD2, false><<<dim3((NN + 63) / 64, DD2 / 64), 256, 0, stream>>>(
            zbuf, W1 + (size_t)l * DD * DD2, b1 + l * DD2, nullptr, nullptr, z1);

        hipMemsetAsync(stats, 0, 768 * 4, stream);
        stats_kernel<DD2><<<(NN + 127) / 128, DD2, 0, stream>>>(z1, stats, stats + 256);
        bn_finalize_kernel<DD2><<<1, DD2, 0, stream>>>(stats, stats + 256, bn1_g + l * DD2,
                                                       bn1_b + l * DD2, sbuf, sbuf + 256);

        gemm_kernel<DD2, DD, true><<<dim3((NN + 63) / 64, DD / 64), 256, 0, stream>>>(
            z1, W2 + (size_t)l * DD2 * DD, b2 + l * DD, sbuf, sbuf + 256, z2);

        stats_kernel<DD><<<(NN + 127) / 128, DD, 0, stream>>>(z2, stats + 512, stats + 640);
        bn_finalize_kernel<DD><<<1, DD, 0, stream>>>(stats + 512, stats + 640, bn_g + l * DD,
                                                     bn_b + l * DD, sbuf + 512, sbuf + 640);

        apply_bn_kernel<<<(NN * DD + 255) / 256, 256, 0, stream>>>(
            z2, sbuf + 512, sbuf + 640, (l == LL - 1) ? (float*)d_out : h, (l < LL - 1) ? 1 : 0);
    }
}

// Round 3
// 1445.202 us; speedup vs baseline: 1.4888x; 1.4888x over previous
//
#include <hip/hip_runtime.h>

#define NN 50000
#define EE 600000
#define DD 128
#define DD2 256
#define LL 5
#define BN_EPS 1e-5f

typedef __attribute__((ext_vector_type(8))) _Float16 half8;
typedef __attribute__((ext_vector_type(4))) float f32x4;

__device__ inline unsigned short f2h_bits(float f) {
    _Float16 h = (_Float16)f;  // RTNE
    return __builtin_bit_cast(unsigned short, h);
}

// ---------------- CSR build ----------------

__global__ void hist_kernel(const int* __restrict__ dst, int* __restrict__ counts) {
    int e = blockIdx.x * blockDim.x + threadIdx.x;
    if (e < EE) atomicAdd(&counts[dst[e]], 1);
}

__global__ void scan1_kernel(const int* __restrict__ counts, int* __restrict__ row_ptr,
                             int* __restrict__ blksum) {
    __shared__ int tmp[256];
    int i = blockIdx.x * 256 + threadIdx.x;
    int v = (i < NN) ? counts[i] : 0;
    tmp[threadIdx.x] = v;
    __syncthreads();
    for (int off = 1; off < 256; off <<= 1) {
        int x = 0;
        if (threadIdx.x >= off) x = tmp[threadIdx.x - off];
        __syncthreads();
        if (threadIdx.x >= off) tmp[threadIdx.x] += x;
        __syncthreads();
    }
    if (i < NN) row_ptr[i] = tmp[threadIdx.x] - v;
    if (threadIdx.x == 255) blksum[blockIdx.x] = tmp[255];
}

__global__ void scan2_kernel(int* __restrict__ blksum, int nblocks) {
    __shared__ int tmp[256];
    int v = (threadIdx.x < nblocks) ? blksum[threadIdx.x] : 0;
    tmp[threadIdx.x] = v;
    __syncthreads();
    for (int off = 1; off < 256; off <<= 1) {
        int x = 0;
        if (threadIdx.x >= off) x = tmp[threadIdx.x - off];
        __syncthreads();
        if (threadIdx.x >= off) tmp[threadIdx.x] += x;
        __syncthreads();
    }
    blksum[threadIdx.x] = tmp[threadIdx.x] - v;
}

__global__ void scan3_kernel(int* __restrict__ row_ptr, const int* __restrict__ blksum) {
    int i = blockIdx.x * 256 + threadIdx.x;
    if (i < NN) row_ptr[i] += blksum[blockIdx.x];
    if (i == 0) row_ptr[NN] = EE;
}

// scatter + pack edge data: edata[p] = {src, a0|a1<<8|a2<<16, w_bits, 0}
__global__ void scatter_kernel(const int* __restrict__ dst, const int* __restrict__ src,
                               const int* __restrict__ edge_attr, const float* __restrict__ ew,
                               const int* __restrict__ row_ptr, int* __restrict__ cursor,
                               int4* __restrict__ edata) {
    int e = blockIdx.x * blockDim.x + threadIdx.x;
    if (e < EE) {
        int d = dst[e];
        int p = row_ptr[d] + atomicAdd(&cursor[d], 1);
        int4 v;
        v.x = src[e];
        v.y = edge_attr[3 * e + 0] | (edge_attr[3 * e + 1] << 8) | (edge_attr[3 * e + 2] << 16);
        v.z = __float_as_int(ew[e]);
        v.w = 0;
        edata[p] = v;
    }
}

// ---------------- W transpose to fp16: Wt[l][m][k] = fp16(W[l][k][m]) ----------------

template <int K, int M>
__global__ void transpose_w_kernel(const float* __restrict__ W, unsigned short* __restrict__ Wt) {
    int idx = blockIdx.x * 256 + threadIdx.x;  // over L*K*M
    if (idx >= LL * K * M) return;
    int l = idx / (K * M);
    int rem = idx - l * K * M;
    int k = rem / M;
    int m = rem - k * M;
    Wt[(size_t)l * K * M + (size_t)m * K + k] = f2h_bits(W[idx]);
}

// ---------------- node init (fp32 h) ----------------

__global__ void init_h_kernel(const int* __restrict__ x, const float* __restrict__ atom_emb,
                              float* __restrict__ h) {
    int n = blockIdx.x * 8 + (threadIdx.x >> 5);
    int lane = threadIdx.x & 31;
    if (n >= NN) return;
    float a0 = 0.f, a1 = 0.f, a2 = 0.f, a3 = 0.f;
#pragma unroll
    for (int f = 0; f < 9; f++) {
        int idx = x[n * 9 + f];
        const float4 v = *(const float4*)(atom_emb + ((size_t)(f * 64 + idx) * DD) + lane * 4);
        a0 += v.x; a1 += v.y; a2 += v.z; a3 += v.w;
    }
    float4 o; o.x = a0; o.y = a1; o.z = a2; o.w = a3;
    *(float4*)(h + (size_t)n * DD + lane * 4) = o;
}

// ---------------- edge aggregate → A fp16 ----------------
// A = fp16( (1+eps)*h + sum_{e: dst=n} relu(h[src]+ea)*w )

__global__ void agg_kernel(const float* __restrict__ h, const int* __restrict__ row_ptr,
                           const int4* __restrict__ edata, const float* __restrict__ bond_l,
                           const float* __restrict__ eps_ptr, unsigned short* __restrict__ Aout) {
    int n = blockIdx.x * 8 + (threadIdx.x >> 5);
    int lane = threadIdx.x & 31;
    if (n >= NN) return;
    int beg = row_ptr[n], end = row_ptr[n + 1];
    float a0 = 0.f, a1 = 0.f, a2 = 0.f, a3 = 0.f;
    for (int i = beg; i < end; i++) {
        int4 ed = edata[i];
        int s = ed.x;
        int at = ed.y;
        float w = __int_as_float(ed.z);
        const float4 hv = *(const float4*)(h + (size_t)s * DD + lane * 4);
        const float4 b0 = *(const float4*)(bond_l + (size_t)((at & 0xff)) * DD + lane * 4);
        const float4 b1 = *(const float4*)(bond_l + (size_t)(8 + ((at >> 8) & 0xff)) * DD + lane * 4);
        const float4 b2 = *(const float4*)(bond_l + (size_t)(16 + ((at >> 16) & 0xff)) * DD + lane * 4);
        float m0 = fmaxf(hv.x + b0.x + b1.x + b2.x, 0.f);
        float m1 = fmaxf(hv.y + b0.y + b1.y + b2.y, 0.f);
        float m2 = fmaxf(hv.z + b0.z + b1.z + b2.z, 0.f);
        float m3 = fmaxf(hv.w + b0.w + b1.w + b2.w, 0.f);
        a0 += m0 * w; a1 += m1 * w; a2 += m2 * w; a3 += m3 * w;
    }
    float eps1 = 1.f + eps_ptr[0];
    const float4 hs = *(const float4*)(h + (size_t)n * DD + lane * 4);
    ushort4 o;
    o.x = f2h_bits(eps1 * hs.x + a0);
    o.y = f2h_bits(eps1 * hs.y + a1);
    o.z = f2h_bits(eps1 * hs.z + a2);
    o.w = f2h_bits(eps1 * hs.w + a3);
    *(ushort4*)(Aout + (size_t)n * DD + lane * 4) = o;
}

// ---------------- fp16 MFMA GEMM: C(NN x M) fp32 = A(NN x K) @ Bt^T + bias, fused col stats ----
// A row-major fp16 bits, Bt is [M][K] fp16 bits, C fp32, stats = {sum[M], sumsq[M]} fp32

template <int K, int M>
__global__ __launch_bounds__(256) void mfma_gemm_kernel(const unsigned short* __restrict__ A,
                                                        const unsigned short* __restrict__ Bt,
                                                        const float* __restrict__ bias,
                                                        float* __restrict__ C,
                                                        float* __restrict__ stats) {
    int wave = threadIdx.x >> 6;
    int lane = threadIdx.x & 63;
    int wr = wave >> 1, wc = wave & 1;
    int row0 = blockIdx.x * 64 + wr * 32;
    int col0 = blockIdx.y * 64 + wc * 32;
    int lr = lane & 15;
    int q = lane >> 4;

    f32x4 acc[2][2];
#pragma unroll
    for (int i = 0; i < 2; i++)
#pragma unroll
        for (int j = 0; j < 2; j++) acc[i][j] = (f32x4){0.f, 0.f, 0.f, 0.f};

#pragma unroll
    for (int k0 = 0; k0 < K; k0 += 32) {
        half8 a[2], b[2];
#pragma unroll
        for (int i = 0; i < 2; i++) {
            int row = row0 + i * 16 + lr;
            int4 t = {0, 0, 0, 0};
            if (row < NN) t = *(const int4*)(A + (size_t)row * K + k0 + q * 8);
            a[i] = __builtin_bit_cast(half8, t);
        }
#pragma unroll
        for (int j = 0; j < 2; j++) {
            int col = col0 + j * 16 + lr;
            int4 t = *(const int4*)(Bt + (size_t)col * K + k0 + q * 8);
            b[j] = __builtin_bit_cast(half8, t);
        }
#pragma unroll
        for (int i = 0; i < 2; i++)
#pragma unroll
            for (int j = 0; j < 2; j++)
                acc[i][j] = __builtin_amdgcn_mfma_f32_16x16x32_f16(a[i], b[j], acc[i][j], 0, 0, 0);
    }

    // epilogue: D element (row = row0 + i*16 + q*4 + r, col = col0 + j*16 + lr)
#pragma unroll
    for (int j = 0; j < 2; j++) {
        int c = col0 + j * 16 + lr;
        float bi = bias[c];
        float s = 0.f, sq = 0.f;
#pragma unroll
        for (int i = 0; i < 2; i++) {
#pragma unroll
            for (int r = 0; r < 4; r++) {
                int row = row0 + i * 16 + q * 4 + r;
                float v = 0.f;
                if (row < NN) {
                    v = acc[i][j][r] + bi;
                    C[(size_t)row * M + c] = v;
                }
                s += v;
                sq += v * v;
            }
        }
        s += __shfl_xor(s, 16);
        s += __shfl_xor(s, 32);
        sq += __shfl_xor(sq, 16);
        sq += __shfl_xor(sq, 32);
        if (q == 0) {
            atomicAdd(&stats[c], s);
            atomicAdd(&stats[M + c], sq);
        }
    }
}

// ---------------- BN finalize ----------------

__global__ void bn_finalize_kernel(const float* __restrict__ stats, const float* __restrict__ g,
                                   const float* __restrict__ b, float* __restrict__ s_out,
                                   float* __restrict__ t_out, int M) {
    int c = threadIdx.x;
    if (c >= M) return;
    float mean = stats[c] * (1.f / NN);
    float var = stats[M + c] * (1.f / NN) - mean * mean;
    float sc = g[c] * rsqrtf(var + BN_EPS);
    s_out[c] = sc;
    t_out[c] = b[c] - mean * sc;
}

// ---------------- BN apply 1: z1 fp32 -> fp16 with relu (4 elems/thread, M=256) ----------------

__global__ void bnapply1_kernel(const float* __restrict__ z, const float* __restrict__ s,
                                const float* __restrict__ t, unsigned short* __restrict__ o) {
    int i = (blockIdx.x * 256 + threadIdx.x) * 4;  // NN*256 total
    int c = i & 255;
    float4 in = *(const float4*)(z + i);
    float v0 = fmaxf(in.x * s[c] + t[c], 0.f);
    float v1 = fmaxf(in.y * s[c + 1] + t[c + 1], 0.f);
    float v2 = fmaxf(in.z * s[c + 2] + t[c + 2], 0.f);
    float v3 = fmaxf(in.w * s[c + 3] + t[c + 3], 0.f);
    ushort4 out;
    out.x = f2h_bits(v0); out.y = f2h_bits(v1);
    out.z = f2h_bits(v2); out.w = f2h_bits(v3);
    *(ushort4*)(o + i) = out;
}

// ---------------- BN apply 2: z2 fp32 -> fp32 out (optional relu), M=128 ----------------

__global__ void bnapply2_kernel(const float* __restrict__ z, const float* __restrict__ s,
                                const float* __restrict__ t, float* __restrict__ o, int do_relu) {
    int i = (blockIdx.x * 256 + threadIdx.x) * 4;  // NN*128 total
    int c = i & 127;
    float4 in = *(const float4*)(z + i);
    float v0 = in.x * s[c] + t[c];
    float v1 = in.y * s[c + 1] + t[c + 1];
    float v2 = in.z * s[c + 2] + t[c + 2];
    float v3 = in.w * s[c + 3] + t[c + 3];
    if (do_relu) {
        v0 = fmaxf(v0, 0.f); v1 = fmaxf(v1, 0.f);
        v2 = fmaxf(v2, 0.f); v3 = fmaxf(v3, 0.f);
    }
    float4 out; out.x = v0; out.y = v1; out.z = v2; out.w = v3;
    *(float4*)(o + i) = out;
}

// ---------------- launch ----------------

extern "C" void kernel_launch(void* const* d_in, const int* in_sizes, int n_in,
                              void* d_out, int out_size, void* d_ws, size_t ws_size,
                              hipStream_t stream) {
    const int* x = (const int*)d_in[0];
    const int* edge_index = (const int*)d_in[1];
    const int* edge_attr = (const int*)d_in[2];
    const float* edge_weight = (const float*)d_in[3];
    const float* atom_emb = (const float*)d_in[4];
    const float* bond_emb = (const float*)d_in[5];
    const float* W1 = (const float*)d_in[6];
    const float* b1 = (const float*)d_in[7];
    const float* bn1_g = (const float*)d_in[8];
    const float* bn1_b = (const float*)d_in[9];
    const float* W2 = (const float*)d_in[10];
    const float* b2 = (const float*)d_in[11];
    const float* eps_p = (const float*)d_in[12];
    const float* bn_g = (const float*)d_in[13];
    const float* bn_b = (const float*)d_in[14];
    const int* srcv = edge_index;
    const int* dstv = edge_index + EE;

    char* p = (char*)d_ws;
    auto alloc = [&](size_t bytes) {
        void* r = (void*)p;
        p += (bytes + 255) & ~(size_t)255;
        return r;
    };
    float* h = (float*)alloc((size_t)NN * DD * 4);                 // fp32 node state
    // shared block: first half holds A1h fp16 [NN*DD]; whole holds z2 fp32 [NN*DD]
    char* blockA = (char*)alloc((size_t)NN * DD * 4);
    unsigned short* A1h = (unsigned short*)blockA;                 // agg out fp16
    float* z2 = (float*)blockA;                                    // gemm2 out fp32 (A1h dead by then)
    float* z1 = (float*)alloc((size_t)NN * DD2 * 4);               // gemm1 out fp32
    unsigned short* z1h = (unsigned short*)alloc((size_t)NN * DD2 * 2);  // bn1+relu fp16
    int4* edata = (int4*)alloc((size_t)EE * 16);
    int* counts = (int*)alloc((size_t)NN * 4);
    int* row_ptr = (int*)alloc((size_t)(NN + 1) * 4);
    int* blksum = (int*)alloc(256 * 4);
    unsigned short* W1t = (unsigned short*)alloc((size_t)LL * DD * DD2 * 2);
    unsigned short* W2t = (unsigned short*)alloc((size_t)LL * DD * DD2 * 2);
    float* stats = (float*)alloc(1024 * 4);   // sum1[256] sq1[256] | sum2[128] sq2[128]
    float* sbuf = (float*)alloc(1024 * 4);    // s1[256] t1[256] s2[128] t2[128]

    // --- one-time prep: CSR + packed edge data + W transposes + h0 ---
    hipMemsetAsync(counts, 0, (size_t)NN * 4, stream);
    hist_kernel<<<(EE + 255) / 256, 256, 0, stream>>>(dstv, counts);
    int nblk = (NN + 255) / 256;
    scan1_kernel<<<nblk, 256, 0, stream>>>(counts, row_ptr, blksum);
    scan2_kernel<<<1, 256, 0, stream>>>(blksum, nblk);
    scan3_kernel<<<nblk, 256, 0, stream>>>(row_ptr, blksum);
    hipMemsetAsync(counts, 0, (size_t)NN * 4, stream);
    scatter_kernel<<<(EE + 255) / 256, 256, 0, stream>>>(dstv, srcv, edge_attr, edge_weight,
                                                         row_ptr, counts, edata);
    transpose_w_kernel<DD, DD2><<<(LL * DD * DD2 + 255) / 256, 256, 0, stream>>>(W1, W1t);
    transpose_w_kernel<DD2, DD><<<(LL * DD * DD2 + 255) / 256, 256, 0, stream>>>(W2, W2t);
    init_h_kernel<<<(NN + 7) / 8, 256, 0, stream>>>(x, atom_emb, h);

    for (int l = 0; l < LL; l++) {
        agg_kernel<<<(NN + 7) / 8, 256, 0, stream>>>(h, row_ptr, edata,
                                                     bond_emb + (size_t)l * 3 * 8 * DD,
                                                     eps_p + l, A1h);

        hipMemsetAsync(stats, 0, 1024 * 4, stream);
        mfma_gemm_kernel<DD, DD2><<<dim3((NN + 63) / 64, DD2 / 64), 256, 0, stream>>>(
            A1h, W1t + (size_t)l * DD * DD2, b1 + l * DD2, z1, stats);
        bn_finalize_kernel<<<1, 256, 0, stream>>>(stats, bn1_g + l * DD2, bn1_b + l * DD2,
                                                  sbuf, sbuf + 256, DD2);
        bnapply1_kernel<<<(NN * DD2 / 4 + 255) / 256, 256, 0, stream>>>(z1, sbuf, sbuf + 256, z1h);

        mfma_gemm_kernel<DD2, DD><<<dim3((NN + 63) / 64, DD / 64), 256, 0, stream>>>(
            z1h, W2t + (size_t)l * DD * DD2, b2 + l * DD, z2, stats + 512);
        bn_finalize_kernel<<<1, 128, 0, stream>>>(stats + 512, bn_g + l * DD, bn_b + l * DD,
                                                  sbuf + 512, sbuf + 640, DD);
        bnapply2_kernel<<<(NN * DD / 4 + 255) / 256, 256, 0, stream>>>(
            z2, sbuf + 512, sbuf + 640, (l == LL - 1) ? (float*)d_out : h, (l < LL - 1) ? 1 : 0);
    }
}